// Round 6
// baseline (248.706 us; speedup 1.0000x reference)
//
#include <hip/hip_runtime.h>
#include <stdint.h>

#define B_ 8
#define N_ 2048
#define D_ 768

typedef unsigned short u16;
typedef unsigned int u32;
typedef __attribute__((ext_vector_type(8))) short bf16x8;
typedef __attribute__((ext_vector_type(8))) unsigned short u16x8;
typedef __attribute__((ext_vector_type(4))) float f32x4;

static constexpr float INV_SCALE = 0.10825317547305482f; // 3/sqrt(768)

__device__ __forceinline__ u16 f2bf(float f) {
  union { float f; unsigned u; } v; v.f = f;
  return (u16)((v.u + 0x7FFFu + ((v.u >> 16) & 1u)) >> 16);
}
__device__ __forceinline__ float bf2f(u16 h) {
  union { unsigned u; float f; } v; v.u = ((unsigned)h) << 16;
  return v.f;
}
__device__ __forceinline__ f32x4 mfma16(bf16x8 a, bf16x8 b, f32x4 c) {
  return __builtin_amdgcn_mfma_f32_16x16x32_bf16(a, b, c, 0, 0, 0);
}
__device__ __forceinline__ void gl_lds16(const u16* g, u16* l) {
  __builtin_amdgcn_global_load_lds(
      (const __attribute__((address_space(1))) u32*)g,
      (__attribute__((address_space(3))) u32*)l, 16, 0, 0);
}

// ---------------- K0: cast x, Wq, Wk, Wv to bf16 ----------------
__global__ __launch_bounds__(256) void cast_kernel(
    const float* __restrict__ x, const float* __restrict__ wq,
    const float* __restrict__ wk, const float* __restrict__ wv,
    u16* __restrict__ xb, u16* __restrict__ wqb,
    u16* __restrict__ wkb, u16* __restrict__ wvb) {
  const long NX = (long)B_ * N_ * D_;
  const long NW = (long)D_ * D_;
  long i = ((long)blockIdx.x * 256 + threadIdx.x) * 8;
  const float* src; u16* dst; long off;
  if (i < NX) { src = x; dst = xb; off = i; }
  else {
    long j = i - NX;
    int seg = (int)(j / NW);
    off = j - (long)seg * NW;
    src = seg == 0 ? wq : (seg == 1 ? wk : wv);
    dst = seg == 0 ? wqb : (seg == 1 ? wkb : wvb);
  }
  float4 a = *(const float4*)(src + off);
  float4 b = *(const float4*)(src + off + 4);
  u16x8 o;
  o[0]=f2bf(a.x); o[1]=f2bf(a.y); o[2]=f2bf(a.z); o[3]=f2bf(a.w);
  o[4]=f2bf(b.x); o[5]=f2bf(b.y); o[6]=f2bf(b.z); o[7]=f2bf(b.w);
  *(u16x8*)(dst + off) = o;
}

// ---- 128x128 BK=32 GEMM core: STATIC 3-buffer, prefetch distance 3 ----
// Phase t (buf X = t%3, all compile-time):
//   vmcnt(8) + barrier  -> tile t (issued 3 phases ago) visible to all waves
//   ds_read + MFMA      -> compiler-scheduled lgkm interleave; waves overlap:
//                          one wave's MFMA co-issues with another's ds_read
//   clobber + barrier   -> every wave's reads of X consumed (WAR-safe)
//   STAGE(t+3 -> X)     -> 4 async gl_lds, no wait
// Counted vmcnt never 0 in main loop; tail drains 8->4->0.
// Swizzle pair (verified: conflicts=0): writer pre-swizzles global col,
// reader swizzles ds_read slot; same involution both sides.
template<int KSTEPS>
__device__ __forceinline__ void gemm_main(
    const u16* __restrict__ Ag, long lda,
    const u16* __restrict__ Bg, long ldb,
    f32x4 (&acc)[4][4]) {
  __shared__ u16 A0[4096], A1[4096], A2[4096];
  __shared__ u16 B0[4096], B1[4096], B2[4096];
  const int t_ = threadIdx.x, l = t_ & 63, w = t_ >> 6;
  const int lr = l & 15;
  const int srow = l >> 2;
  const int scol = (((l & 3) ^ ((l >> 3) & 3)) * 8);
  const int ar = (w >> 1) * 64, br = (w & 1) * 64;
  const int rslot = (((l >> 4) ^ ((lr >> 1) & 3)) * 8);

  auto STAGE = [&](u16* As, u16* Bs, int kt) {
    const int kofs = kt * 32;
    #pragma unroll
    for (int c = 0; c < 2; ++c) {
      int ch = w * 2 + c;
      gl_lds16(Ag + (long)(ch * 16 + srow) * lda + kofs + scol, As + ch * 512);
      gl_lds16(Bg + (long)(ch * 16 + srow) * ldb + kofs + scol, Bs + ch * 512);
    }
  };

#define PH(AS, BS, VM, DOSTAGE, ST)                                \
  {                                                                \
    asm volatile("s_waitcnt vmcnt(" #VM ")" ::: "memory");         \
    __builtin_amdgcn_s_barrier();                                  \
    asm volatile("" ::: "memory");                                 \
    bf16x8 a[4], bb[4];                                            \
    _Pragma("unroll")                                              \
    for (int mf = 0; mf < 4; ++mf)                                 \
      a[mf] = *(const bf16x8*)(AS + (ar + mf * 16 + lr) * 32 + rslot); \
    _Pragma("unroll")                                              \
    for (int nf = 0; nf < 4; ++nf)                                 \
      bb[nf] = *(const bf16x8*)(BS + (br + nf * 16 + lr) * 32 + rslot); \
    __builtin_amdgcn_s_setprio(1);                                 \
    _Pragma("unroll")                                              \
    for (int mf = 0; mf < 4; ++mf)                                 \
      _Pragma("unroll")                                            \
      for (int nf = 0; nf < 4; ++nf)                               \
        acc[mf][nf] = mfma16(a[mf], bb[nf], acc[mf][nf]);          \
    __builtin_amdgcn_s_setprio(0);                                 \
    asm volatile("" ::: "memory");                                 \
    __builtin_amdgcn_s_barrier();                                  \
    if (DOSTAGE) STAGE(AS, BS, ST);                                \
  }

  STAGE(A0, B0, 0);
  STAGE(A1, B1, 1);
  STAGE(A2, B2, 2);
  int t = 0;
  for (; t + 5 < KSTEPS; t += 3) {
    PH(A0, B0, 8, true, t + 3);
    PH(A1, B1, 8, true, t + 4);
    PH(A2, B2, 8, true, t + 5);
  }
  if constexpr (KSTEPS % 3 == 1) {     // e.g. 64: t == KSTEPS-4 here
    PH(A0, B0, 8, true, t + 3);        // stages tile KSTEPS-1
    PH(A1, B1, 8, false, 0);
    PH(A2, B2, 4, false, 0);
    PH(A0, B0, 0, false, 0);
  } else {                              // KSTEPS % 3 == 0: t == KSTEPS-3
    PH(A0, B0, 8, false, 0);
    PH(A1, B1, 4, false, 0);
    PH(A2, B2, 0, false, 0);
  }
#undef PH
}

// ---------------- K1: Q/K/V = x @ W^T + b (Q scaled) ----------------
// grid 2304; XCD = rt-band: each XCD's x slice (16 rt = 3 MB) fits its L2.
__global__ __launch_bounds__(256) void qkv_gemm(
    const u16* __restrict__ xb,
    const u16* __restrict__ wq, const u16* __restrict__ wk, const u16* __restrict__ wv,
    const float* __restrict__ bq, const float* __restrict__ bk, const float* __restrict__ bv,
    u16* __restrict__ Qs, u16* __restrict__ Kb, u16* __restrict__ Vb) {
  const int lin = blockIdx.x;
  const int xcd = lin & 7, inner = lin >> 3;          // inner: 0..287
  const int rt = xcd * 16 + (inner & 15);
  const int ct = (inner >> 4) % 6;
  const int mat = inner / 96;
  const u16* W = mat == 0 ? wq : (mat == 1 ? wk : wv);
  const float* bias = mat == 0 ? bq : (mat == 1 ? bk : bv);
  u16* out = mat == 0 ? Qs : (mat == 1 ? Kb : Vb);
  const float scl = mat == 0 ? INV_SCALE : 1.0f;
  const int rbase = rt * 128, cbase = ct * 128;

  f32x4 acc[4][4] = {};
  gemm_main<D_ / 32>(xb + (long)rbase * D_, D_, W + (long)cbase * D_, D_, acc);

  const int l = threadIdx.x & 63, w = threadIdx.x >> 6;
  const int lr = l & 15, orow = (l >> 4) * 4;
  const int ar = (w >> 1) * 64, br = (w & 1) * 64;
  #pragma unroll
  for (int mf = 0; mf < 4; ++mf)
    #pragma unroll
    for (int nf = 0; nf < 4; ++nf) {
      int col = cbase + br + nf * 16 + lr;
      float bc = bias[col];
      #pragma unroll
      for (int r = 0; r < 4; ++r) {
        int row = rbase + ar + mf * 16 + orow + r;
        out[(long)row * D_ + col] = f2bf((acc[mf][nf][r] + bc) * scl);
      }
    }
}

// ---------------- K2: P = exp(Q.K^T), den partials ----------------
// grid 2048; XCD = one b; kblk fastest.
__global__ __launch_bounds__(256) void qk_exp(
    const u16* __restrict__ Qs, const u16* __restrict__ Kb,
    u16* __restrict__ P, float* __restrict__ denpart) {
  __shared__ float dl[2][128];
  const int lin = blockIdx.x;
  const int L = (lin & 7) * 256 + (lin >> 3);
  const int kblk = L % 16, qblk = (L / 16) % 16, b = L / 256;

  f32x4 acc[4][4] = {};
  gemm_main<D_ / 32>(Qs + ((long)b * N_ + qblk * 128) * D_, D_,
                     Kb + ((long)b * N_ + kblk * 128) * D_, D_, acc);

  const int tt = threadIdx.x, l = tt & 63, w = tt >> 6;
  const int lr = l & 15, orow = (l >> 4) * 4;
  const int ar = (w >> 1) * 64, br = (w & 1) * 64;
  float csum[4] = {0.f, 0.f, 0.f, 0.f};
  #pragma unroll
  for (int mf = 0; mf < 4; ++mf)
    #pragma unroll
    for (int nf = 0; nf < 4; ++nf) {
      long kk = kblk * 128 + br + nf * 16 + lr;
      #pragma unroll
      for (int r = 0; r < 4; ++r) {
        long q = qblk * 128 + ar + mf * 16 + orow + r;
        float e = __expf(acc[mf][nf][r]);
        u16 pe = f2bf(e);
        P[((long)b * N_ + q) * N_ + kk] = pe;
        csum[nf] += bf2f(pe);
      }
    }
  #pragma unroll
  for (int nf = 0; nf < 4; ++nf) {
    csum[nf] += __shfl_xor(csum[nf], 16);
    csum[nf] += __shfl_xor(csum[nf], 32);
  }
  __syncthreads();
  if (l < 16) {
    #pragma unroll
    for (int nf = 0; nf < 4; ++nf)
      dl[w >> 1][br + nf * 16 + l] = csum[nf];
  }
  __syncthreads();
  if (tt < 128)
    denpart[((long)qblk * B_ + b) * N_ + kblk * 128 + tt] = dl[0][tt] + dl[1][tt];
}

// ---------------- K3: VsT[b][d][k] = V[b][k][d] / den[b][k] ----------------
__global__ __launch_bounds__(256) void scale_transpose(
    const u16* __restrict__ Vb, const float* __restrict__ denpart,
    u16* __restrict__ VsT) {
  const int b = blockIdx.z, k0 = blockIdx.y * 64, d0 = blockIdx.x * 64;
  __shared__ float tile[64][65];
  __shared__ float invden[64];
  const int t = threadIdx.x;
  if (t < 64) {
    float s = 0.f;
    for (int qs = 0; qs < 16; ++qs)
      s += denpart[((long)qs * B_ + b) * N_ + k0 + t];
    invden[t] = 1.0f / s;
  }
  __syncthreads();
  for (int idx = t; idx < 4096; idx += 256) {
    int kl = idx >> 6, dl = idx & 63;
    float v = bf2f(Vb[((long)b * N_ + k0 + kl) * D_ + d0 + dl]) * invden[kl];
    tile[dl][kl] = v;
  }
  __syncthreads();
  for (int idx = t; idx < 4096; idx += 256) {
    int dl = idx >> 6, kl = idx & 63;
    VsT[((long)b * D_ + d0 + dl) * N_ + k0 + kl] = f2bf(tile[dl][kl]);
  }
}

// ---------------- K4: out = P @ Vs + xb (bf16 residual) ----------------
// grid 768; XCD = one b (96 blocks): VsT_b (3MB) stays L2-hot.
__global__ __launch_bounds__(256) void pv_gemm(
    const u16* __restrict__ P, const u16* __restrict__ VsT,
    const u16* __restrict__ xb, float* __restrict__ out) {
  const int lin = blockIdx.x;
  const int L = (lin & 7) * 96 + (lin >> 3);
  const int qt = L % 16, dt = (L / 16) % 6, b = L / 96;
  const int q0 = qt * 128, d0 = dt * 128;

  f32x4 acc[4][4] = {};
  gemm_main<N_ / 32>(P + ((long)b * N_ + q0) * N_, N_,
                     VsT + ((long)b * D_ + d0) * N_, N_, acc);

  const int l = threadIdx.x & 63, w = threadIdx.x >> 6;
  const int lr = l & 15, orow = (l >> 4) * 4;
  const int ar = (w >> 1) * 64, br = (w & 1) * 64;
  #pragma unroll
  for (int mf = 0; mf < 4; ++mf)
    #pragma unroll
    for (int nf = 0; nf < 4; ++nf) {
      int dd = d0 + br + nf * 16 + lr;
      #pragma unroll
      for (int r = 0; r < 4; ++r) {
        int q = q0 + ar + mf * 16 + orow + r;
        long idx = ((long)b * N_ + q) * D_ + dd;
        out[idx] = acc[mf][nf][r] + bf2f(xb[idx]);
      }
    }
}

extern "C" void kernel_launch(void* const* d_in, const int* in_sizes, int n_in,
                              void* d_out, int out_size, void* d_ws, size_t ws_size,
                              hipStream_t stream) {
  const float* x  = (const float*)d_in[0];
  const float* Wq = (const float*)d_in[1];
  const float* bq = (const float*)d_in[2];
  const float* Wk = (const float*)d_in[3];
  const float* bk = (const float*)d_in[4];
  const float* Wv = (const float*)d_in[5];
  const float* bv = (const float*)d_in[6];

  char* ws = (char*)d_ws;
  u16* xb  = (u16*)(ws + 0);                          // 25165824 B (live to pv)
  u16* wqb = (u16*)(ws + 25165824);
  u16* wkb = (u16*)(ws + 26345472);
  u16* wvb = (u16*)(ws + 27525120);
  u16* Qs  = (u16*)(ws + 28704768);
  u16* Kb  = (u16*)(ws + 53870592);
  u16* Vb  = (u16*)(ws + 79036416);
  u16* VsT = (u16*)(ws + 104202240);
  u16* P   = (u16*)(ws + 129368064);                  // 67108864 B
  float* denpart = (float*)(ws + 196476928);          // 1048576 B
  (void)in_sizes; (void)n_in; (void)out_size; (void)ws_size;

  cast_kernel<<<7008, 256, 0, stream>>>(x, Wq, Wk, Wv, xb, wqb, wkb, wvb);
  qkv_gemm<<<2304, 256, 0, stream>>>(xb, wqb, wkb, wvb, bq, bk, bv, Qs, Kb, Vb);
  qk_exp<<<2048, 256, 0, stream>>>(Qs, Kb, P, denpart);
  scale_transpose<<<dim3(12, 32, 8), 256, 0, stream>>>(Vb, denpart, VsT);
  pv_gemm<<<768, 256, 0, stream>>>(P, VsT, xb, (float*)d_out);
}

// Round 7
// 225.244 us; speedup vs baseline: 1.1042x; 1.1042x over previous
//
#include <hip/hip_runtime.h>
#include <stdint.h>

#define B_ 8
#define N_ 2048
#define D_ 768

typedef unsigned short u16;
typedef unsigned int u32;
typedef __attribute__((ext_vector_type(8))) short bf16x8;
typedef __attribute__((ext_vector_type(8))) unsigned short u16x8;
typedef __attribute__((ext_vector_type(4))) float f32x4;

static constexpr float INV_SCALE = 0.10825317547305482f; // 3/sqrt(768)

__device__ __forceinline__ u16 f2bf(float f) {
  union { float f; unsigned u; } v; v.f = f;
  return (u16)((v.u + 0x7FFFu + ((v.u >> 16) & 1u)) >> 16);
}
__device__ __forceinline__ float bf2f(u16 h) {
  union { unsigned u; float f; } v; v.u = ((unsigned)h) << 16;
  return v.f;
}
__device__ __forceinline__ f32x4 mfma16(bf16x8 a, bf16x8 b, f32x4 c) {
  return __builtin_amdgcn_mfma_f32_16x16x32_bf16(a, b, c, 0, 0, 0);
}
__device__ __forceinline__ void gl_lds16(const u16* g, u16* l) {
  __builtin_amdgcn_global_load_lds(
      (const __attribute__((address_space(1))) u32*)g,
      (__attribute__((address_space(3))) u32*)l, 16, 0, 0);
}

// ---------------- K0: cast x, Wq, Wk, Wv to bf16 ----------------
__global__ __launch_bounds__(256) void cast_kernel(
    const float* __restrict__ x, const float* __restrict__ wq,
    const float* __restrict__ wk, const float* __restrict__ wv,
    u16* __restrict__ xb, u16* __restrict__ wqb,
    u16* __restrict__ wkb, u16* __restrict__ wvb) {
  const long NX = (long)B_ * N_ * D_;
  const long NW = (long)D_ * D_;
  long i = ((long)blockIdx.x * 256 + threadIdx.x) * 8;
  const float* src; u16* dst; long off;
  if (i < NX) { src = x; dst = xb; off = i; }
  else {
    long j = i - NX;
    int seg = (int)(j / NW);
    off = j - (long)seg * NW;
    src = seg == 0 ? wq : (seg == 1 ? wk : wv);
    dst = seg == 0 ? wqb : (seg == 1 ? wkb : wvb);
  }
  float4 a = *(const float4*)(src + off);
  float4 b = *(const float4*)(src + off + 4);
  u16x8 o;
  o[0]=f2bf(a.x); o[1]=f2bf(a.y); o[2]=f2bf(a.z); o[3]=f2bf(a.w);
  o[4]=f2bf(b.x); o[5]=f2bf(b.y); o[6]=f2bf(b.z); o[7]=f2bf(b.w);
  *(u16x8*)(dst + off) = o;
}

// ---- 128x256 BK=32 GEMM core: 4 waves, wave tile 128x64 ----
// Intensity: 12 KB LDS reads -> 32 MFMA (524 kFLOP) per wave-phase = 43.7 F/B
// (vs 32.8 for 64x64 wave tiles) -> MFMA pipe co-dominant with LDS pipe.
// Pipeline: STATIC 3-buffer, prefetch distance 3, counted vmcnt 12/6/0
// (6 gl_lds per wave-phase, 2 tiles in flight mid-loop, never vmcnt 0).
// Swizzle pair (verified R3-R6: conflicts=0): writer pre-swizzles global col,
// reader swizzles ds_read slot; same involution both sides.
template<int KSTEPS>
__device__ __forceinline__ void gemm_main(
    const u16* __restrict__ Ag, long lda,
    const u16* __restrict__ Bg, long ldb,
    f32x4 (&acc)[8][4]) {
  __shared__ u16 A0[4096], A1[4096], A2[4096];    // 128 x 32
  __shared__ u16 B0[8192], B1[8192], B2[8192];    // 256 x 32
  const int t_ = threadIdx.x, l = t_ & 63, w = t_ >> 6;
  const int lr = l & 15;
  const int srow = l >> 2;
  const int scol = (((l & 3) ^ ((l >> 3) & 3)) * 8);
  const int wc = w * 64;                              // wave's B-col base
  const int rslot = (((l >> 4) ^ ((lr >> 1) & 3)) * 8);

  auto STAGE = [&](u16* As, u16* Bs, int kt) {
    const int kofs = kt * 32;
    #pragma unroll
    for (int c = 0; c < 6; ++c) {
      int ch = w * 6 + c;                              // 24 chunks: 8 A + 16 B
      if (ch < 8)
        gl_lds16(Ag + (long)(ch * 16 + srow) * lda + kofs + scol, As + ch * 512);
      else
        gl_lds16(Bg + (long)((ch - 8) * 16 + srow) * ldb + kofs + scol,
                 Bs + (ch - 8) * 512);
    }
  };

#define PH(AS, BS, VM, DOSTAGE, ST)                                \
  {                                                                \
    asm volatile("s_waitcnt vmcnt(" #VM ")" ::: "memory");         \
    __builtin_amdgcn_s_barrier();                                  \
    asm volatile("" ::: "memory");                                 \
    bf16x8 a[8], bb[4];                                            \
    _Pragma("unroll")                                              \
    for (int mf = 0; mf < 8; ++mf)                                 \
      a[mf] = *(const bf16x8*)(AS + (mf * 16 + lr) * 32 + rslot);  \
    _Pragma("unroll")                                              \
    for (int nf = 0; nf < 4; ++nf)                                 \
      bb[nf] = *(const bf16x8*)(BS + (wc + nf * 16 + lr) * 32 + rslot); \
    __builtin_amdgcn_s_setprio(1);                                 \
    _Pragma("unroll")                                              \
    for (int mf = 0; mf < 8; ++mf)                                 \
      _Pragma("unroll")                                            \
      for (int nf = 0; nf < 4; ++nf)                               \
        acc[mf][nf] = mfma16(a[mf], bb[nf], acc[mf][nf]);          \
    __builtin_amdgcn_s_setprio(0);                                 \
    asm volatile("" ::: "memory");                                 \
    __builtin_amdgcn_s_barrier();                                  \
    if (DOSTAGE) STAGE(AS, BS, ST);                                \
  }

  STAGE(A0, B0, 0);
  STAGE(A1, B1, 1);
  STAGE(A2, B2, 2);
  int t = 0;
  for (; t + 5 < KSTEPS; t += 3) {
    PH(A0, B0, 12, true, t + 3);
    PH(A1, B1, 12, true, t + 4);
    PH(A2, B2, 12, true, t + 5);
  }
  if constexpr (KSTEPS % 3 == 1) {     // e.g. 64: t == KSTEPS-4 here
    PH(A0, B0, 12, true, t + 3);       // stages tile KSTEPS-1 into buf 0
    PH(A1, B1, 12, false, 0);
    PH(A2, B2, 6, false, 0);
    PH(A0, B0, 0, false, 0);
  } else {                              // KSTEPS % 3 == 0: t == KSTEPS-3
    PH(A0, B0, 12, false, 0);
    PH(A1, B1, 6, false, 0);
    PH(A2, B2, 0, false, 0);
  }
#undef PH
}

// ---------------- K1: Q/K/V = x @ W^T + b (Q scaled) ----------------
// grid 1152 = 128 rt x 3 ct x 3 mat; XCD = rt-band (16 rt = 3 MB xb slice).
__global__ __launch_bounds__(256, 2) void qkv_gemm(
    const u16* __restrict__ xb,
    const u16* __restrict__ wq, const u16* __restrict__ wk, const u16* __restrict__ wv,
    const float* __restrict__ bq, const float* __restrict__ bk, const float* __restrict__ bv,
    u16* __restrict__ Qs, u16* __restrict__ Kb, u16* __restrict__ Vb) {
  const int lin = blockIdx.x;
  const int xcd = lin & 7, inner = lin >> 3;          // inner: 0..143
  const int rt = xcd * 16 + (inner & 15);
  const int rest = inner >> 4;                        // 0..8
  const int ct = rest % 3, mat = rest / 3;
  const u16* W = mat == 0 ? wq : (mat == 1 ? wk : wv);
  const float* bias = mat == 0 ? bq : (mat == 1 ? bk : bv);
  u16* out = mat == 0 ? Qs : (mat == 1 ? Kb : Vb);
  const float scl = mat == 0 ? INV_SCALE : 1.0f;
  const int rbase = rt * 128, cbase = ct * 256;

  f32x4 acc[8][4] = {};
  gemm_main<D_ / 32>(xb + (long)rbase * D_, D_, W + (long)cbase * D_, D_, acc);

  const int l = threadIdx.x & 63, w = threadIdx.x >> 6;
  const int lr = l & 15, orow = (l >> 4) * 4, wc = w * 64;
  #pragma unroll
  for (int mf = 0; mf < 8; ++mf)
    #pragma unroll
    for (int nf = 0; nf < 4; ++nf) {
      int col = cbase + wc + nf * 16 + lr;
      float bc = bias[col];
      #pragma unroll
      for (int r = 0; r < 4; ++r) {
        int row = rbase + mf * 16 + orow + r;
        out[(long)row * D_ + col] = f2bf((acc[mf][nf][r] + bc) * scl);
      }
    }
}

// ---------------- K2: P = exp(Q.K^T), den partials ----------------
// grid 1024 = 8 kblk x 16 qblk x 8 b; XCD = one b; kblk fastest.
__global__ __launch_bounds__(256, 2) void qk_exp(
    const u16* __restrict__ Qs, const u16* __restrict__ Kb,
    u16* __restrict__ P, float* __restrict__ denpart) {
  const int lin = blockIdx.x;
  const int L = (lin & 7) * 128 + (lin >> 3);
  const int kblk = L % 8, qblk = (L / 8) % 16, b = L / 128;

  f32x4 acc[8][4] = {};
  gemm_main<D_ / 32>(Qs + ((long)b * N_ + qblk * 128) * D_, D_,
                     Kb + ((long)b * N_ + kblk * 256) * D_, D_, acc);

  const int tt = threadIdx.x, l = tt & 63, w = tt >> 6;
  const int lr = l & 15, orow = (l >> 4) * 4, wc = w * 64;
  float csum[4] = {0.f, 0.f, 0.f, 0.f};
  #pragma unroll
  for (int mf = 0; mf < 8; ++mf)
    #pragma unroll
    for (int nf = 0; nf < 4; ++nf) {
      long kk = kblk * 256 + wc + nf * 16 + lr;
      #pragma unroll
      for (int r = 0; r < 4; ++r) {
        long q = qblk * 128 + mf * 16 + orow + r;
        float e = __expf(acc[mf][nf][r]);
        u16 pe = f2bf(e);
        P[((long)b * N_ + q) * N_ + kk] = pe;
        csum[nf] += bf2f(pe);
      }
    }
  // sum over the 4 orow lane-groups -> full 128-q column sums; waves own
  // disjoint 64-col ranges -> direct global write, no LDS pass.
  #pragma unroll
  for (int nf = 0; nf < 4; ++nf) {
    csum[nf] += __shfl_xor(csum[nf], 16);
    csum[nf] += __shfl_xor(csum[nf], 32);
  }
  if (l < 16) {
    #pragma unroll
    for (int nf = 0; nf < 4; ++nf)
      denpart[((long)qblk * B_ + b) * N_ + kblk * 256 + wc + nf * 16 + l] = csum[nf];
  }
}

// ---------------- K3: VsT[b][d][k] = V[b][k][d] / den[b][k] ----------------
__global__ __launch_bounds__(256) void scale_transpose(
    const u16* __restrict__ Vb, const float* __restrict__ denpart,
    u16* __restrict__ VsT) {
  const int b = blockIdx.z, k0 = blockIdx.y * 64, d0 = blockIdx.x * 64;
  __shared__ float tile[64][65];
  __shared__ float invden[64];
  const int t = threadIdx.x;
  if (t < 64) {
    float s = 0.f;
    for (int qs = 0; qs < 16; ++qs)
      s += denpart[((long)qs * B_ + b) * N_ + k0 + t];
    invden[t] = 1.0f / s;
  }
  __syncthreads();
  for (int idx = t; idx < 4096; idx += 256) {
    int kl = idx >> 6, dl = idx & 63;
    float v = bf2f(Vb[((long)b * N_ + k0 + kl) * D_ + d0 + dl]) * invden[kl];
    tile[dl][kl] = v;
  }
  __syncthreads();
  for (int idx = t; idx < 4096; idx += 256) {
    int dl = idx >> 6, kl = idx & 63;
    VsT[((long)b * D_ + d0 + dl) * N_ + k0 + kl] = f2bf(tile[dl][kl]);
  }
}

// ---------------- K4: out = P @ Vs + xb (bf16 residual) ----------------
// grid 384 = 16 qt x 3 dt x 8 b; XCD = one b (48 blocks): VsT_b L2-hot.
__global__ __launch_bounds__(256, 2) void pv_gemm(
    const u16* __restrict__ P, const u16* __restrict__ VsT,
    const u16* __restrict__ xb, float* __restrict__ out) {
  const int lin = blockIdx.x;
  const int L = (lin & 7) * 48 + (lin >> 3);
  const int qt = L % 16, dt = (L / 16) % 3, b = L / 48;
  const int q0 = qt * 128, d0 = dt * 256;

  f32x4 acc[8][4] = {};
  gemm_main<N_ / 32>(P + ((long)b * N_ + q0) * N_, N_,
                     VsT + ((long)b * D_ + d0) * N_, N_, acc);

  const int l = threadIdx.x & 63, w = threadIdx.x >> 6;
  const int lr = l & 15, orow = (l >> 4) * 4, wc = w * 64;
  #pragma unroll
  for (int mf = 0; mf < 8; ++mf)
    #pragma unroll
    for (int nf = 0; nf < 4; ++nf) {
      int dd = d0 + wc + nf * 16 + lr;
      #pragma unroll
      for (int r = 0; r < 4; ++r) {
        int q = q0 + mf * 16 + orow + r;
        long idx = ((long)b * N_ + q) * D_ + dd;
        out[idx] = acc[mf][nf][r] + bf2f(xb[idx]);
      }
    }
}

extern "C" void kernel_launch(void* const* d_in, const int* in_sizes, int n_in,
                              void* d_out, int out_size, void* d_ws, size_t ws_size,
                              hipStream_t stream) {
  const float* x  = (const float*)d_in[0];
  const float* Wq = (const float*)d_in[1];
  const float* bq = (const float*)d_in[2];
  const float* Wk = (const float*)d_in[3];
  const float* bk = (const float*)d_in[4];
  const float* Wv = (const float*)d_in[5];
  const float* bv = (const float*)d_in[6];

  char* ws = (char*)d_ws;
  u16* xb  = (u16*)(ws + 0);                          // 25165824 B (live to pv)
  u16* wqb = (u16*)(ws + 25165824);
  u16* wkb = (u16*)(ws + 26345472);
  u16* wvb = (u16*)(ws + 27525120);
  u16* Qs  = (u16*)(ws + 28704768);
  u16* Kb  = (u16*)(ws + 53870592);
  u16* Vb  = (u16*)(ws + 79036416);
  u16* VsT = (u16*)(ws + 104202240);
  u16* P   = (u16*)(ws + 129368064);                  // 67108864 B
  float* denpart = (float*)(ws + 196476928);          // 1048576 B
  (void)in_sizes; (void)n_in; (void)out_size; (void)ws_size;

  cast_kernel<<<7008, 256, 0, stream>>>(x, Wq, Wk, Wv, xb, wqb, wkb, wvb);
  qkv_gemm<<<1152, 256, 0, stream>>>(xb, wqb, wkb, wvb, bq, bk, bv, Qs, Kb, Vb);
  qk_exp<<<1024, 256, 0, stream>>>(Qs, Kb, P, denpart);
  scale_transpose<<<dim3(12, 32, 8), 256, 0, stream>>>(Vb, denpart, VsT);
  pv_gemm<<<384, 256, 0, stream>>>(P, VsT, xb, (float*)d_out);
}